// Round 11
// baseline (11225.028 us; speedup 1.0000x reference)
//
#include <hip/hip_runtime.h>
#include <math.h>

// T=1000, B=256, F_IN=13 x3 -> 39 features, H=100, 3H=300 (gate order r,z,n), 20 classes
#define T_STEPS 1000
#define BATCH   256
#define FIN     13
#define XDIM    39
#define HDIM    100
#define G3      300
#define NCLS    20
#define NTHR    960      // 3 thread-parts per gate row; parts are wave-aligned (5 waves each)
#define VLEN    160      // V = [x(39)+pad(1) | h(100) | zero-pad(20)]
#define CHUNK   52       // floats per part = 13 float4

__device__ __forceinline__ float fast_sigmoid(float v) {
    return 1.f / (1.f + __expf(-v));
}
__device__ __forceinline__ float fast_tanh(float v) {
    const float c = fminf(fmaxf(v, -15.f), 15.f);
    const float e = __expf(2.f * c);
    return (e - 1.f) / (e + 1.f);
}

// R4-R10 lesson chain:
//  - LLVM always remats invariant weight loads rather than keeping them
//    resident -> R8's loop does 52 global loads/thread/STEP -> L1/L2-port
//    bound at 931us.
//  - gfx950 VALU can NOT read an AGPR source directly (R10 compile error);
//    AGPRs are reachable only via v_accvgpr_read_b32.
// So: stage the 52 weights into AGPRs once (v_accvgpr_write, "=a", volatile),
// and each step read them back with explicit VOLATILE v_accvgpr_read + fmaf.
// Volatile keeps the reads inside the loop (no 52-wide live range -> no
// spill); asm is opaque (no remat); reads are full-rate VALU ops with zero
// memory-system traffic. Total regs/thread ~ 52 AGPR + ~50 VGPR <= 128
// budget for 4 waves/SIMD (launch_bounds(960,4): 15 waves, busiest SIMD 4).
#define AGPR_WRITE(dst, src) \
    asm volatile("v_accvgpr_write_b32 %0, %1" : "=a"(dst) : "v"(src))
#define RFMA(acc, areg, xval) \
    do { float _t; \
         asm volatile("v_accvgpr_read_b32 %0, %1" : "=v"(_t) : "a"(areg)); \
         acc = fmaf(_t, (xval), acc); } while (0)

//   p0: V[0:52)   = x(39)+pad (+ zero-weight tail)
//   p1: V[40:92)  = h[0:52)
//   p2: V[92:144) = h[52:100) + zero-pad
__launch_bounds__(NTHR, 4)
__global__ void gru_persistent(const float* __restrict__ mfcc0,
                               const float* __restrict__ mfcc1,
                               const float* __restrict__ mfcc2,
                               const float* __restrict__ len0,
                               const float* __restrict__ W_ih,
                               const float* __restrict__ W_hh,
                               const float* __restrict__ b_ih,
                               const float* __restrict__ b_hh,
                               const float* __restrict__ W_out,
                               const float* __restrict__ b_out,
                               float* __restrict__ out)
{
    const int b   = blockIdx.x;
    const int tid = threadIdx.x;
    const int p   = tid / 320;                    // part 0,1,2 (wave-aligned)
    const int g0  = tid % 320;                    // row id within part
    const int g   = (g0 < G3) ? g0 : (G3 - 1);    // clamped; stores guarded by g0

    __shared__ __align__(16) float V[2][VLEN];    // [x | h | pad] ping-pong
    __shared__ float part[3 * G3];                // partial dot per (p, row)
    __shared__ float feat[2 * HDIM];

    // ---- one-time setup (uniform control flow; scalars only) ----
    const float* src = (p == 0) ? (W_ih + g * XDIM)
                                : (W_hh + g * HDIM + ((p == 2) ? CHUNK : 0));
    const int   c    = (p == 0) ? XDIM : ((p == 1) ? CHUNK : (HDIM - CHUNK));
    const float bias = (p == 0) ? b_ih[g] : ((p == 1) ? b_hh[g] : 0.f);
    const int   vb0  = (p == 0) ? 0 : ((p == 1) ? 10 : 23);   // float4-unit base

    // ---- load 52 weights and park them in AGPRs (resident for all 1000 steps) ----
    float k00,k01,k02,k03,k04,k05,k06,k07,k08,k09,k10,k11,k12;
    float k13,k14,k15,k16,k17,k18,k19,k20,k21,k22,k23,k24,k25;
    float k26,k27,k28,k29,k30,k31,k32,k33,k34,k35,k36,k37,k38;
    float k39,k40,k41,k42,k43,k44,k45,k46,k47,k48,k49,k50,k51;
#define LDW(i) (((i) < c) ? src[(i)] : 0.f)
    AGPR_WRITE(k00,LDW( 0)); AGPR_WRITE(k01,LDW( 1)); AGPR_WRITE(k02,LDW( 2)); AGPR_WRITE(k03,LDW( 3));
    AGPR_WRITE(k04,LDW( 4)); AGPR_WRITE(k05,LDW( 5)); AGPR_WRITE(k06,LDW( 6)); AGPR_WRITE(k07,LDW( 7));
    AGPR_WRITE(k08,LDW( 8)); AGPR_WRITE(k09,LDW( 9)); AGPR_WRITE(k10,LDW(10)); AGPR_WRITE(k11,LDW(11));
    AGPR_WRITE(k12,LDW(12)); AGPR_WRITE(k13,LDW(13)); AGPR_WRITE(k14,LDW(14)); AGPR_WRITE(k15,LDW(15));
    AGPR_WRITE(k16,LDW(16)); AGPR_WRITE(k17,LDW(17)); AGPR_WRITE(k18,LDW(18)); AGPR_WRITE(k19,LDW(19));
    AGPR_WRITE(k20,LDW(20)); AGPR_WRITE(k21,LDW(21)); AGPR_WRITE(k22,LDW(22)); AGPR_WRITE(k23,LDW(23));
    AGPR_WRITE(k24,LDW(24)); AGPR_WRITE(k25,LDW(25)); AGPR_WRITE(k26,LDW(26)); AGPR_WRITE(k27,LDW(27));
    AGPR_WRITE(k28,LDW(28)); AGPR_WRITE(k29,LDW(29)); AGPR_WRITE(k30,LDW(30)); AGPR_WRITE(k31,LDW(31));
    AGPR_WRITE(k32,LDW(32)); AGPR_WRITE(k33,LDW(33)); AGPR_WRITE(k34,LDW(34)); AGPR_WRITE(k35,LDW(35));
    AGPR_WRITE(k36,LDW(36)); AGPR_WRITE(k37,LDW(37)); AGPR_WRITE(k38,LDW(38)); AGPR_WRITE(k39,LDW(39));
    AGPR_WRITE(k40,LDW(40)); AGPR_WRITE(k41,LDW(41)); AGPR_WRITE(k42,LDW(42)); AGPR_WRITE(k43,LDW(43));
    AGPR_WRITE(k44,LDW(44)); AGPR_WRITE(k45,LDW(45)); AGPR_WRITE(k46,LDW(46)); AGPR_WRITE(k47,LDW(47));
    AGPR_WRITE(k48,LDW(48)); AGPR_WRITE(k49,LDW(49)); AGPR_WRITE(k50,LDW(50)); AGPR_WRITE(k51,LDW(51));
#undef LDW

    // ---- per-thread x streaming source (threads 0..38, all in part 0) ----
    const float* xsrc = mfcc0;
    int xoff = 0;
    if (tid < XDIM) {
        const int f = tid % FIN;
        xsrc = (tid < FIN) ? mfcc0 : (tid < 2 * FIN ? mfcc1 : mfcc2);
        xoff = b * FIN + f;
    }

    // ---- init: zero both V buffers (h=0, pads=0), then x(t=0) ----
    if (tid < VLEN) { V[0][tid] = 0.f; V[1][tid] = 0.f; }
    if (tid < XDIM) V[0][tid] = xsrc[xoff];
    __syncthreads();

    float sum = 0.f;
    float mx  = -INFINITY;

    for (int t = 0; t < T_STEPS; ++t) {
        const int cur = t & 1;
        const int nxt = cur ^ 1;

        float xpf = 0.f;   // prefetch x(t+1) during compute
        if (tid < XDIM && (t + 1) < T_STEPS)
            xpf = xsrc[(size_t)(t + 1) * (BATCH * FIN) + xoff];

        // ---- phase A: 13 broadcast float4 reads x 4 AGPR-read+FMA ----
        const float4* V4 = (const float4*)V[cur];
        float a0 = 0.f, a1 = 0.f, a2 = 0.f, a3 = 0.f;
        float4 vv;
        vv = V4[vb0+ 0]; RFMA(a0,k00,vv.x); RFMA(a1,k01,vv.y); RFMA(a2,k02,vv.z); RFMA(a3,k03,vv.w);
        vv = V4[vb0+ 1]; RFMA(a0,k04,vv.x); RFMA(a1,k05,vv.y); RFMA(a2,k06,vv.z); RFMA(a3,k07,vv.w);
        vv = V4[vb0+ 2]; RFMA(a0,k08,vv.x); RFMA(a1,k09,vv.y); RFMA(a2,k10,vv.z); RFMA(a3,k11,vv.w);
        vv = V4[vb0+ 3]; RFMA(a0,k12,vv.x); RFMA(a1,k13,vv.y); RFMA(a2,k14,vv.z); RFMA(a3,k15,vv.w);
        vv = V4[vb0+ 4]; RFMA(a0,k16,vv.x); RFMA(a1,k17,vv.y); RFMA(a2,k18,vv.z); RFMA(a3,k19,vv.w);
        vv = V4[vb0+ 5]; RFMA(a0,k20,vv.x); RFMA(a1,k21,vv.y); RFMA(a2,k22,vv.z); RFMA(a3,k23,vv.w);
        vv = V4[vb0+ 6]; RFMA(a0,k24,vv.x); RFMA(a1,k25,vv.y); RFMA(a2,k26,vv.z); RFMA(a3,k27,vv.w);
        vv = V4[vb0+ 7]; RFMA(a0,k28,vv.x); RFMA(a1,k29,vv.y); RFMA(a2,k30,vv.z); RFMA(a3,k31,vv.w);
        vv = V4[vb0+ 8]; RFMA(a0,k32,vv.x); RFMA(a1,k33,vv.y); RFMA(a2,k34,vv.z); RFMA(a3,k35,vv.w);
        vv = V4[vb0+ 9]; RFMA(a0,k36,vv.x); RFMA(a1,k37,vv.y); RFMA(a2,k38,vv.z); RFMA(a3,k39,vv.w);
        vv = V4[vb0+10]; RFMA(a0,k40,vv.x); RFMA(a1,k41,vv.y); RFMA(a2,k42,vv.z); RFMA(a3,k43,vv.w);
        vv = V4[vb0+11]; RFMA(a0,k44,vv.x); RFMA(a1,k45,vv.y); RFMA(a2,k46,vv.z); RFMA(a3,k47,vv.w);
        vv = V4[vb0+12]; RFMA(a0,k48,vv.x); RFMA(a1,k49,vv.y); RFMA(a2,k50,vv.z); RFMA(a3,k51,vv.w);

        if (g0 < G3)
            part[p * G3 + g0] = bias + ((a0 + a1) + (a2 + a3));
        if (tid < XDIM) V[nxt][tid] = xpf;         // stage x(t+1)
        __syncthreads();

        // ---- phase B: nonlinearity + state update (threads 0..99) ----
        if (tid < HDIM) {
            const float r  = fast_sigmoid(part[tid] + part[G3 + tid] + part[2*G3 + tid]);
            const float z  = fast_sigmoid(part[HDIM + tid] + part[G3 + HDIM + tid] + part[2*G3 + HDIM + tid]);
            const float hn = part[G3 + 2*HDIM + tid] + part[2*G3 + 2*HDIM + tid];  // includes b_hh
            const float n  = fast_tanh(fmaf(r, hn, part[2*HDIM + tid]));           // i_n includes b_ih
            const float ho = V[cur][XDIM + 1 + tid];
            const float hv = fmaf(z, ho - n, n);   // (1-z)*n + z*h
            V[nxt][XDIM + 1 + tid] = hv;
            sum += hv;
            mx = fmaxf(mx, hv);
        }
        __syncthreads();
    }

    // ---- pooling + output linear ----
    if (tid < HDIM) {
        feat[tid]        = sum / len0[b];
        feat[HDIM + tid] = mx;
    }
    __syncthreads();

    if (tid < NCLS) {
        float acc = b_out[tid];
        #pragma unroll 4
        for (int k = 0; k < 2 * HDIM; ++k)
            acc = fmaf(W_out[tid * 2 * HDIM + k], feat[k], acc);
        out[b * NCLS + tid] = acc;
    }
}

extern "C" void kernel_launch(void* const* d_in, const int* in_sizes, int n_in,
                              void* d_out, int out_size, void* d_ws, size_t ws_size,
                              hipStream_t stream)
{
    const float* mfcc0 = (const float*)d_in[0];
    const float* mfcc1 = (const float*)d_in[1];
    const float* mfcc2 = (const float*)d_in[2];
    const float* len0  = (const float*)d_in[3];
    const float* W_ih  = (const float*)d_in[4];
    const float* W_hh  = (const float*)d_in[5];
    const float* b_ih  = (const float*)d_in[6];
    const float* b_hh  = (const float*)d_in[7];
    const float* W_out = (const float*)d_in[8];
    const float* b_out = (const float*)d_in[9];
    float* out = (float*)d_out;

    gru_persistent<<<BATCH, NTHR, 0, stream>>>(
        mfcc0, mfcc1, mfcc2, len0, W_ih, W_hh, b_ih, b_hh, W_out, b_out, out);
}

// Round 12
// 2078.070 us; speedup vs baseline: 5.4017x; 5.4017x over previous
//
#include <hip/hip_runtime.h>
#include <math.h>

// T=1000, B=256, F_IN=13 x3 -> 39 features, H=100, 3H=300 (gate order r,z,n), 20 classes
#define T_STEPS 1000
#define BATCH   256
#define FIN     13
#define XDIM    39
#define HDIM    100
#define G3      300
#define NCLS    20
#define NTHR    960      // 3 thread-parts per gate row; parts are wave-aligned (5 waves each)
#define VLEN    160      // V = [x(39)+pad(1) | h(100) | zero-pad(20)]
#define NCH     13       // float4 chunks per part (52 floats)
#define GPAD    304      // padded row count in packed layout (multiple of 16)

__device__ __forceinline__ float fast_sigmoid(float v) {
    return 1.f / (1.f + __expf(-v));
}
__device__ __forceinline__ float fast_tanh(float v) {
    const float c = fminf(fmaxf(v, -15.f), 15.f);
    const float e = __expf(2.f * c);
    return (e - 1.f) / (e + 1.f);
}

// R4-R11 (7 failed attempts) settled it: this compiler ALWAYS re-fetches
// per-thread weight arrays inside the loop (remat) — pins/AGPRs/attributes
// all lose (R11: AGPR spill -> 8.9 GB scratch traffic, 11 ms). So optimize
// the re-fetch instead: R8's 52 scattered scalar dwords/thread/step (64
// distinct cache lines per wave instr) become 13 COALESCED dwordx4 via a
// lane-transposed packed layout in d_ws:
//     wT4[(i*3 + p)*GPAD + g]   (i = chunk 0..12, p = part, g = row)
// -> consecutive lanes read consecutive float4s: 1 KB/wave-instr from
// ~8-16 lines. TA instrs per CU-step: 780 -> 195.
__global__ void pack_weights(const float* __restrict__ W_ih,
                             const float* __restrict__ W_hh,
                             float* __restrict__ wT)
{
    const int idx   = blockIdx.x * blockDim.x + threadIdx.x;
    const int total = NCH * 3 * GPAD * 4;          // 47424 scalars
    if (idx >= total) return;
    const int e    = idx & 3;
    const int rest = idx >> 2;                     // (i*3+p)*GPAD + g
    const int g    = rest % GPAD;
    const int ip   = rest / GPAD;
    const int p    = ip % 3;
    const int i    = ip / 3;
    const int j    = 4 * i + e;                    // element within the 52-chunk
    float v = 0.f;
    if (g < G3) {
        if (p == 0) {
            if (j < XDIM) v = W_ih[g * XDIM + j];          // x-part (V[0:39))
        } else if (p == 1) {
            if (j < 52)   v = W_hh[g * HDIM + j];          // h[0:52)
        } else {
            if (j < 48)   v = W_hh[g * HDIM + 52 + j];     // h[52:100)
        }
    }
    wT[idx] = v;
}

__device__ __forceinline__ void fma4(const float4& wv, const float4& xv,
                                     float& a0, float& a1, float& a2, float& a3)
{
    a0 = fmaf(wv.x, xv.x, a0);
    a1 = fmaf(wv.y, xv.y, a1);
    a2 = fmaf(wv.z, xv.z, a2);
    a3 = fmaf(wv.w, xv.w, a3);
}

//   p0: V[0:52)   = x(39)+pad (+ zero-weight tail covering h[0:12))
//   p1: V[40:92)  = h[0:52)
//   p2: V[92:144) = h[52:100) + zero-pad
__launch_bounds__(NTHR, 4)
__global__ void gru_persistent(const float* __restrict__ mfcc0,
                               const float* __restrict__ mfcc1,
                               const float* __restrict__ mfcc2,
                               const float* __restrict__ len0,
                               const float* __restrict__ wT,     // packed weights (d_ws)
                               const float* __restrict__ b_ih,
                               const float* __restrict__ b_hh,
                               const float* __restrict__ W_out,
                               const float* __restrict__ b_out,
                               float* __restrict__ out)
{
    const int b   = blockIdx.x;
    const int tid = threadIdx.x;
    const int p   = tid / 320;                    // part 0,1,2 (wave-aligned)
    const int g0  = tid % 320;                    // row id within part
    const int g   = (g0 < G3) ? g0 : (G3 - 1);    // clamped; stores guarded by g0

    __shared__ __align__(16) float V[2][VLEN];    // [x | h | pad] ping-pong
    __shared__ float part[3 * G3];                // partial dot per (p, row)
    __shared__ float feat[2 * HDIM];

    const float bias = (p == 0) ? b_ih[g] : ((p == 1) ? b_hh[g] : 0.f);
    const int   vb0  = (p == 0) ? 0 : ((p == 1) ? 10 : 23);   // float4-unit base in V
    const float4* wT4 = (const float4*)wT;
    const int   wbase = p * GPAD + g;             // lane-transposed: +i*3*GPAD per chunk

    // ---- per-thread x streaming source (threads 0..38, all in part 0) ----
    const float* xsrc = mfcc0;
    int xoff = 0;
    if (tid < XDIM) {
        const int f = tid % FIN;
        xsrc = (tid < FIN) ? mfcc0 : (tid < 2 * FIN ? mfcc1 : mfcc2);
        xoff = b * FIN + f;
    }

    // ---- init: zero both V buffers (h=0, pads=0), then x(t=0) ----
    if (tid < VLEN) { V[0][tid] = 0.f; V[1][tid] = 0.f; }
    if (tid < XDIM) V[0][tid] = xsrc[xoff];
    __syncthreads();

    float sum = 0.f;
    float mx  = -INFINITY;

    for (int t = 0; t < T_STEPS; ++t) {
        const int cur = t & 1;
        const int nxt = cur ^ 1;

        float xpf = 0.f;   // prefetch x(t+1) during compute
        if (tid < XDIM && (t + 1) < T_STEPS)
            xpf = xsrc[(size_t)(t + 1) * (BATCH * FIN) + xoff];

        // ---- phase A: 13 coalesced dwordx4 weight loads + 13 broadcast LDS reads ----
        const float4* V4 = (const float4*)V[cur];
        float a0 = 0.f, a1 = 0.f, a2 = 0.f, a3 = 0.f;
        #pragma unroll
        for (int i = 0; i < NCH; ++i) {
            const float4 wv = wT4[wbase + i * (3 * GPAD)];
            const float4 xv = V4[vb0 + i];
            fma4(wv, xv, a0, a1, a2, a3);
        }

        if (g0 < G3)
            part[p * G3 + g0] = bias + ((a0 + a1) + (a2 + a3));
        if (tid < XDIM) V[nxt][tid] = xpf;         // stage x(t+1)
        __syncthreads();

        // ---- phase B: nonlinearity + state update (threads 0..99) ----
        if (tid < HDIM) {
            // issue all 8 part reads up front (latency overlap)
            const float q0r = part[tid];
            const float q1r = part[G3 + tid];
            const float q2r = part[2*G3 + tid];
            const float q0z = part[HDIM + tid];
            const float q1z = part[G3 + HDIM + tid];
            const float q2z = part[2*G3 + HDIM + tid];
            const float q0n = part[2*HDIM + tid];                 // i_n (incl b_ih)
            const float q1n = part[G3 + 2*HDIM + tid];            // h_n low (incl b_hh)
            const float q2n = part[2*G3 + 2*HDIM + tid];          // h_n high
            const float ho  = V[cur][XDIM + 1 + tid];
            const float r  = fast_sigmoid(q0r + q1r + q2r);
            const float z  = fast_sigmoid(q0z + q1z + q2z);
            const float n  = fast_tanh(fmaf(r, q1n + q2n, q0n));
            const float hv = fmaf(z, ho - n, n);   // (1-z)*n + z*h
            V[nxt][XDIM + 1 + tid] = hv;
            sum += hv;
            mx = fmaxf(mx, hv);
        }
        __syncthreads();
    }

    // ---- pooling + output linear ----
    if (tid < HDIM) {
        feat[tid]        = sum / len0[b];
        feat[HDIM + tid] = mx;
    }
    __syncthreads();

    if (tid < NCLS) {
        float acc = b_out[tid];
        #pragma unroll 4
        for (int k = 0; k < 2 * HDIM; ++k)
            acc = fmaf(W_out[tid * 2 * HDIM + k], feat[k], acc);
        out[b * NCLS + tid] = acc;
    }
}

extern "C" void kernel_launch(void* const* d_in, const int* in_sizes, int n_in,
                              void* d_out, int out_size, void* d_ws, size_t ws_size,
                              hipStream_t stream)
{
    const float* mfcc0 = (const float*)d_in[0];
    const float* mfcc1 = (const float*)d_in[1];
    const float* mfcc2 = (const float*)d_in[2];
    const float* len0  = (const float*)d_in[3];
    const float* W_ih  = (const float*)d_in[4];
    const float* W_hh  = (const float*)d_in[5];
    const float* b_ih  = (const float*)d_in[6];
    const float* b_hh  = (const float*)d_in[7];
    const float* W_out = (const float*)d_in[8];
    const float* b_out = (const float*)d_in[9];
    float* out = (float*)d_out;
    float* wT  = (float*)d_ws;     // 13*3*304*4 floats = 189,696 B

    const int total = NCH * 3 * GPAD * 4;
    pack_weights<<<(total + 255) / 256, 256, 0, stream>>>(W_ih, W_hh, wT);
    gru_persistent<<<BATCH, NTHR, 0, stream>>>(
        mfcc0, mfcc1, mfcc2, len0, wT, b_ih, b_hh, W_out, b_out, out);
}

// Round 13
// 1583.121 us; speedup vs baseline: 7.0904x; 1.3126x over previous
//
#include <hip/hip_runtime.h>
#include <math.h>

// T=1000, B=256, F_IN=13 x3 -> 39 features, H=100, 3H=300 (gate order r,z,n), 20 classes
#define T_STEPS 1000
#define BATCH   256
#define FIN     13
#define XDIM    39
#define HDIM    100
#define G3      300
#define NCLS    20
#define NTHR    960     // 3 parts x 320 rows, wave-aligned (5 waves/part)
#define NW      7       // uint4 (8-half) chunks per thread = 56 halves
#define VH      160     // V halves: [x(39)|pad(1)|h(100)|pad(20)]

typedef _Float16 h2v __attribute__((ext_vector_type(2)));
__device__ __forceinline__ h2v u2h(unsigned u) {
    union { unsigned u; h2v h; } x; x.u = u; return x.h;
}

__device__ __forceinline__ float fast_sigmoid(float v) {
    return 1.f / (1.f + __expf(-v));
}
__device__ __forceinline__ float fast_tanh(float v) {
    const float c = fminf(fmaxf(v, -15.f), 15.f);
    const float e = __expf(2.f * c);
    return (e - 1.f) / (e + 1.f);
}

// R4-R12 conclusion: the kernel is weight-REFETCH-BW-bound (~75 B/cyc/CU
// delivered; R8's 167 KB fp32/CU/step = 2237 cyc = the 931us plateau) and the
// compiler structurally refuses weight residency (7 failed attempts: remat /
// alloca / AGPR spill). Only bytes can move: fp16 weights via v_dot2_f32_f16
// (fp32 accumulate). h STATE stays fp32 in a shadow array -> quantization hits
// only dot operands, no error compounding through the recurrence.
// Packed layout (d_ws): row (p*320+g) = 56 halves (7 uint4, 112 B, 16B-align):
//   p0: V-halves[0:56)   -> w[j]= j<39 ? W_ih[g][j] : 0
//   p1: V-halves[40:96)  -> w[j]= j<52 ? W_hh[g][j] : 0      (h[0:52))
//   p2: V-halves[88:144) -> w[j]= 4<=j<52 ? W_hh[g][48+j] : 0 (h[52:100))
__global__ void pack_weights(const float* __restrict__ W_ih,
                             const float* __restrict__ W_hh,
                             _Float16* __restrict__ wH)
{
    const int idx = blockIdx.x * blockDim.x + threadIdx.x;
    const int total = NTHR * 8 * NW;               // 53760 halves
    if (idx >= total) return;
    const int j   = idx % (8 * NW);
    const int row = idx / (8 * NW);
    const int p   = row / 320;
    const int g   = row % 320;
    float v = 0.f;
    if (g < G3) {
        if (p == 0)      { if (j < XDIM)           v = W_ih[g * XDIM + j]; }
        else if (p == 1) { if (j < 52)             v = W_hh[g * HDIM + j]; }
        else             { if (j >= 4 && j < 52)   v = W_hh[g * HDIM + 48 + j]; }
    }
    wH[idx] = (_Float16)v;
}

__launch_bounds__(NTHR, 4)
__global__ void gru_persistent(const float* __restrict__ mfcc0,
                               const float* __restrict__ mfcc1,
                               const float* __restrict__ mfcc2,
                               const float* __restrict__ len0,
                               const _Float16* __restrict__ wH,   // packed fp16 (d_ws)
                               const float* __restrict__ b_ih,
                               const float* __restrict__ b_hh,
                               const float* __restrict__ W_out,
                               const float* __restrict__ b_out,
                               float* __restrict__ out)
{
    const int b   = blockIdx.x;
    const int tid = threadIdx.x;
    const int p   = tid / 320;                    // part 0,1,2 (wave-aligned)
    const int g0  = tid % 320;                    // row id within part
    const int g   = (g0 < G3) ? g0 : (G3 - 1);    // clamped; stores guarded by g0

    __shared__ __align__(16) _Float16 Vh[2][VH];  // fp16 dot operand [x|h|pad]
    __shared__ float h32[2][HDIM];                // fp32 STATE (exact recurrence)
    __shared__ float part[3 * G3];                // partial dots
    __shared__ float feat[2 * HDIM];

    const float bias = (p == 0) ? b_ih[g] : ((p == 1) ? b_hh[g] : 0.f);
    const int   vb0  = (p == 0) ? 0 : ((p == 1) ? 5 : 11);   // uint4-unit window base
    const uint4* wrow = (const uint4*)wH + (size_t)(p * 320 + g) * NW;

    // ---- per-thread x streaming source (threads 0..38, all in part 0) ----
    const float* xsrc = mfcc0;
    int xoff = 0;
    if (tid < XDIM) {
        const int f = tid % FIN;
        xsrc = (tid < FIN) ? mfcc0 : (tid < 2 * FIN ? mfcc1 : mfcc2);
        xoff = b * FIN + f;
    }

    // ---- init: zero Vh (both buffers, 320 halves), h32, then x(t=0) ----
    if (tid < 2 * VH) ((_Float16*)Vh)[tid] = (_Float16)0.f;
    if (tid < 2 * HDIM) ((float*)h32)[tid] = 0.f;
    __syncthreads();                               // Vh zeroed before x write
    if (tid < XDIM) Vh[0][tid] = (_Float16)xsrc[xoff];
    __syncthreads();

    float sum = 0.f;
    float mx  = -INFINITY;

    for (int t = 0; t < T_STEPS; ++t) {
        const int cur = t & 1;
        const int nxt = cur ^ 1;

        float xpf = 0.f;   // prefetch x(t+1) during compute
        if (tid < XDIM && (t + 1) < T_STEPS)
            xpf = xsrc[(size_t)(t + 1) * (BATCH * FIN) + xoff];

        // ---- phase A: 7 dwordx4 weight loads + 7 broadcast LDS b128 + 28 fdot2 ----
        const uint4* Vw = (const uint4*)&Vh[cur][0] + vb0;
        float a0 = 0.f, a1 = 0.f, a2 = 0.f, a3 = 0.f;
        #pragma unroll
        for (int i = 0; i < NW; ++i) {
            const uint4 wv = wrow[i];
            const uint4 xv = Vw[i];
            a0 = __builtin_amdgcn_fdot2(u2h(wv.x), u2h(xv.x), a0, false);
            a1 = __builtin_amdgcn_fdot2(u2h(wv.y), u2h(xv.y), a1, false);
            a2 = __builtin_amdgcn_fdot2(u2h(wv.z), u2h(xv.z), a2, false);
            a3 = __builtin_amdgcn_fdot2(u2h(wv.w), u2h(xv.w), a3, false);
        }

        if (g0 < G3)
            part[p * G3 + g0] = bias + ((a0 + a1) + (a2 + a3));
        if (tid < XDIM) Vh[nxt][tid] = (_Float16)xpf;   // stage x(t+1)
        __syncthreads();

        // ---- phase B: nonlinearity + fp32 state update (threads 0..99) ----
        if (tid < HDIM) {
            const float q0r = part[tid];
            const float q1r = part[G3 + tid];
            const float q2r = part[2*G3 + tid];
            const float q0z = part[HDIM + tid];
            const float q1z = part[G3 + HDIM + tid];
            const float q2z = part[2*G3 + HDIM + tid];
            const float q0n = part[2*HDIM + tid];          // i_n (incl b_ih)
            const float q1n = part[G3 + 2*HDIM + tid];     // h_n low (incl b_hh)
            const float q2n = part[2*G3 + 2*HDIM + tid];   // h_n high
            const float ho  = h32[cur][tid];               // fp32 state
            const float r  = fast_sigmoid(q0r + q1r + q2r);
            const float z  = fast_sigmoid(q0z + q1z + q2z);
            const float n  = fast_tanh(fmaf(r, q1n + q2n, q0n));
            const float hv = fmaf(z, ho - n, n);           // (1-z)*n + z*h
            h32[nxt][tid]     = hv;                        // exact state
            Vh[nxt][40 + tid] = (_Float16)hv;              // fp16 dot operand
            sum += hv;
            mx = fmaxf(mx, hv);
        }
        __syncthreads();
    }

    // ---- pooling + output linear ----
    if (tid < HDIM) {
        feat[tid]        = sum / len0[b];
        feat[HDIM + tid] = mx;
    }
    __syncthreads();

    if (tid < NCLS) {
        float acc = b_out[tid];
        #pragma unroll 4
        for (int k = 0; k < 2 * HDIM; ++k)
            acc = fmaf(W_out[tid * 2 * HDIM + k], feat[k], acc);
        out[b * NCLS + tid] = acc;
    }
}

extern "C" void kernel_launch(void* const* d_in, const int* in_sizes, int n_in,
                              void* d_out, int out_size, void* d_ws, size_t ws_size,
                              hipStream_t stream)
{
    const float* mfcc0 = (const float*)d_in[0];
    const float* mfcc1 = (const float*)d_in[1];
    const float* mfcc2 = (const float*)d_in[2];
    const float* len0  = (const float*)d_in[3];
    const float* W_ih  = (const float*)d_in[4];
    const float* W_hh  = (const float*)d_in[5];
    const float* b_ih  = (const float*)d_in[6];
    const float* b_hh  = (const float*)d_in[7];
    const float* W_out = (const float*)d_in[8];
    const float* b_out = (const float*)d_in[9];
    float* out = (float*)d_out;
    _Float16* wH = (_Float16*)d_ws;               // 53760 halves = 105 KB

    const int total = NTHR * 8 * NW;
    pack_weights<<<(total + 255) / 256, 256, 0, stream>>>(W_ih, W_hh, wH);
    gru_persistent<<<BATCH, NTHR, 0, stream>>>(
        mfcc0, mfcc1, mfcc2, len0, wH, b_ih, b_hh, W_out, b_out, out);
}